// Round 8
// baseline (629.207 us; speedup 1.0000x reference)
//
#include <hip/hip_runtime.h>
#include <cstdint>

#define NB 8
#define NN 2048
#define DD 1024
#define DD2 2048

typedef short short8 __attribute__((ext_vector_type(8)));
typedef float floatx4 __attribute__((ext_vector_type(4)));

// fp32 -> bf16 round-to-nearest-even (no NaN special-casing; inputs are finite)
__device__ __forceinline__ unsigned short f2bf(float f) {
    unsigned int u = __float_as_uint(f);
    u += 0x7fffu + ((u >> 16) & 1u);
    return (unsigned short)(u >> 16);
}

// ---------------------------------------------------------------------------
// Kernel 1: per-row L2 norm of x0 = x[:, :, :1024]; write xn (bf16).
// ---------------------------------------------------------------------------
__global__ __launch_bounds__(256) void k_norm(const float* __restrict__ x,
                                              unsigned short* __restrict__ xn) {
    int row  = blockIdx.x * 4 + (threadIdx.x >> 6);
    int lane = threadIdx.x & 63;
    const float* xr = x + (size_t)row * DD2;   // x0 = first 1024 floats of row
    float4 v[4];
    float s = 0.f;
#pragma unroll
    for (int i = 0; i < 4; i++) {
        v[i] = ((const float4*)xr)[lane + i * 64];
        s += v[i].x * v[i].x + v[i].y * v[i].y + v[i].z * v[i].z + v[i].w * v[i].w;
    }
#pragma unroll
    for (int off = 32; off >= 1; off >>= 1) s += __shfl_xor(s, off, 64);
    float inv = 1.0f / sqrtf(s + 1e-8f);
    unsigned short* xnr = xn + (size_t)row * DD;
#pragma unroll
    for (int i = 0; i < 4; i++) {
        ushort4 o;
        o.x = f2bf(v[i].x * inv);
        o.y = f2bf(v[i].y * inv);
        o.z = f2bf(v[i].z * inv);
        o.w = f2bf(v[i].w * inv);
        ((ushort4*)xnr)[lane + i * 64] = o;
    }
}

// ---------------------------------------------------------------------------
// Kernel 2: cast+transpose x0 -> x0t[b][d][n] (bf16), 64x64 LDS tiles.
// ---------------------------------------------------------------------------
__global__ __launch_bounds__(256) void k_transpose(const float* __restrict__ x,
                                                   unsigned short* __restrict__ x0t) {
    __shared__ unsigned short tile[64 * 68];   // stride 68 shorts: 8B-aligned rows, no pow2
    int b  = blockIdx.y;
    int t  = blockIdx.x;       // 0..511
    int nt = t >> 4;           // 0..31
    int dt = t & 15;           // 0..15
    int n0 = nt * 64, d0 = dt * 64;
    int tid = threadIdx.x;
    int r  = tid >> 4;         // 0..15
    int c4 = tid & 15;         // 0..15
    const float* xb = x + (size_t)b * NN * DD2;
#pragma unroll
    for (int p = 0; p < 4; p++) {
        int n = p * 16 + r;
        float4 v = *(const float4*)&xb[(size_t)(n0 + n) * DD2 + d0 + c4 * 4];
        tile[(c4 * 4 + 0) * 68 + n] = f2bf(v.x);
        tile[(c4 * 4 + 1) * 68 + n] = f2bf(v.y);
        tile[(c4 * 4 + 2) * 68 + n] = f2bf(v.z);
        tile[(c4 * 4 + 3) * 68 + n] = f2bf(v.w);
    }
    __syncthreads();
    unsigned short* ob = x0t + (size_t)b * DD * NN;
#pragma unroll
    for (int p = 0; p < 4; p++) {
        int d = p * 16 + r;
        ushort4 o;
        o.x = tile[d * 68 + c4 * 4 + 0];
        o.y = tile[d * 68 + c4 * 4 + 1];
        o.z = tile[d * 68 + c4 * 4 + 2];
        o.w = tile[d * 68 + c4 * 4 + 3];
        *(ushort4*)&ob[(size_t)(d0 + d) * NN + n0 + c4 * 4] = o;
    }
}

// ---------------------------------------------------------------------------
// ZERO-BARRIER register GEMM core. R1-R6 ledger: prefetch depth (1==3), BK
// (32==64), blocks/CU (2==4), and load balance all NULL at ~81 µs with every
// pipe <=27% busy and ~2850 cy per block-iter vs ~770 cy of pipe demand.
// The one invariant across all four was the {global_load_lds -> vmcnt ->
// barrier -> ds_read -> MFMA -> barrier} chain. This core removes it: both
// operand panels are L2/L3-resident (XCD-pinned 4 MB arrays / L3-resident
// attn), so fragments are loaded DIRECTLY from global to VGPR (64B-contiguous
// per row: lanes quad 0..3 cover quad*8..+31 shorts), double-buffered, no
// LDS, no barriers, each wave fully self-paced. Compiler inserts counted
// vmcnt waits for register loads automatically (the known-good case).
// Cost: 2x duplicated panel reads from L2 (two waves share each row) --
// L2 headroom is ~5x. All frag indices static (rule #20) via ping-pong.
// C[128x128] += A[128xK] * B[128xK]^T, 4 waves 2x2, 64x64 per wave.
// kIters (BK=64 units) must be EVEN: cosim 16, ctx (nt+1)*2. VGPR ~220.
// ---------------------------------------------------------------------------
struct Frags { short8 v[4][2]; };

__device__ __forceinline__ void load_frags(Frags& f, const unsigned short* base,
                                           int ld, int kcol) {
#pragma unroll
    for (int t = 0; t < 4; t++)
#pragma unroll
        for (int s = 0; s < 2; s++)
            f.v[t][s] = *(const short8*)(base + (size_t)(t * 16) * ld + kcol + s * 32);
}

__device__ __forceinline__ void mfma_frags(const Frags& a, const Frags& b,
                                           floatx4 acc[4][4]) {
#pragma unroll
    for (int s = 0; s < 2; s++)
#pragma unroll
        for (int ti = 0; ti < 4; ti++)
#pragma unroll
            for (int tj = 0; tj < 4; tj++)
                acc[ti][tj] = __builtin_amdgcn_mfma_f32_16x16x32_bf16(
                    a.v[ti][s], b.v[tj][s], acc[ti][tj], 0, 0, 0);
}

__device__ __forceinline__ void gemm_reg(const unsigned short* __restrict__ Ag, int lda,
                                         const unsigned short* __restrict__ Bg, int ldb,
                                         int kIters,   // even, >= 2
                                         floatx4 acc[4][4]) {
    int tid  = threadIdx.x;
    int w    = tid >> 6, lane = tid & 63;
    int wr   = (w >> 1) * 64, wc = (w & 1) * 64;
    int lrow = lane & 15, quad = lane >> 4;
    // lane's fragment base: row (wr|wc + t*16 + lrow), k-slot quad*8 (+s*32)
    const unsigned short* Ab = Ag + (size_t)(wr + lrow) * lda + quad * 8;
    const unsigned short* Bb = Bg + (size_t)(wc + lrow) * ldb + quad * 8;

    Frags a0, b0, a1, b1;
    load_frags(a0, Ab, lda, 0);
    load_frags(b0, Bb, ldb, 0);
    for (int kt = 0; kt < kIters; kt += 2) {
        load_frags(a1, Ab, lda, (kt + 1) * 64);
        load_frags(b1, Bb, ldb, (kt + 1) * 64);
        mfma_frags(a0, b0, acc);               // waits on a0/b0 loads (counted)
        if (kt + 2 < kIters) {
            load_frags(a0, Ab, lda, (kt + 2) * 64);
            load_frags(b0, Bb, ldb, (kt + 2) * 64);
        }
        mfma_frags(a1, b1, acc);               // waits on a1/b1 loads (counted)
    }
}

// ---------------------------------------------------------------------------
// Kernel 3: attn[b][n][m] = tril(sp)[n][m] * (xn[b][n] . xn[b][m]), bf16 out.
// Flat grid 1088 (R1's best-measured schedule), b = L&7 pins batch -> XCD so
// xn[b] (4 MB) is L2-resident. All items uniform K=1024 (16 iters).
// ---------------------------------------------------------------------------
__global__ __launch_bounds__(256, 2) void k_cosim(const unsigned short* __restrict__ xn,
                                                  const float* __restrict__ sp,
                                                  unsigned short* __restrict__ attn) {
    int L = blockIdx.x;                 // 0..1087
    int b = L & 7;                      // batch == XCD (dispatch round-robins %8)
    int p = L >> 3;                     // 0..135 -> (nt, mt) with mt<=nt
    int nt = 0;
    while ((nt + 1) * (nt + 2) / 2 <= p) nt++;
    int mt = p - nt * (nt + 1) / 2;
    int n0 = nt * 128, m0 = mt * 128;
    const unsigned short* xb = xn + (size_t)b * NN * DD;

    floatx4 acc[4][4];
#pragma unroll
    for (int i = 0; i < 4; i++)
#pragma unroll
        for (int j = 0; j < 4; j++) acc[i][j] = (floatx4)0.0f;

    gemm_reg(xb + (size_t)n0 * DD, DD, xb + (size_t)m0 * DD, DD, DD / 64, acc);

    int tid = threadIdx.x, w = tid >> 6, lane = tid & 63;
    int wr = (w >> 1) * 64, wc = (w & 1) * 64;
    int col = lane & 15, quad = lane >> 4;
    unsigned short* ab = attn + (size_t)b * NN * NN;
#pragma unroll
    for (int ti = 0; ti < 4; ti++)
#pragma unroll
        for (int tj = 0; tj < 4; tj++)
#pragma unroll
            for (int r = 0; r < 4; r++) {
                int n = n0 + wr + ti * 16 + quad * 4 + r;
                int m = m0 + wc + tj * 16 + col;
                float v = acc[ti][tj][r];
                float s = sp[(size_t)n * NN + m];
                float o = (m <= n) ? s * v : 0.0f;   // tril mask (diagonal tiles)
                ab[(size_t)n * NN + m] = f2bf(o);
            }
}

// ---------------------------------------------------------------------------
// Kernel 4: out[b][n][d] = (attn[b][n][:K] . x0t[b][d][:K]) * x1[b][n][d]
// K = (nt+1)*128 (causal). Grid 512, b = L&7 pins batch -> XCD (x0t[b] =
// 4 MB = one L2). Zig-zag pairing: ranks k and 127-k of the desc-by-nt list
// -> every block runs exactly 34 iters (balanced; proven neutral-or-better).
// ---------------------------------------------------------------------------
__global__ __launch_bounds__(256, 2) void k_ctx(const unsigned short* __restrict__ attn,
                                                const unsigned short* __restrict__ x0t,
                                                const float* __restrict__ x,
                                                float* __restrict__ out) {
    int L = blockIdx.x;                 // 0..511
    int b = L & 7;                      // batch == XCD
    int k = L >> 3;                     // 0..63

    int tid = threadIdx.x, w = tid >> 6, lane = tid & 63;
    int wr = (w >> 1) * 64, wc = (w & 1) * 64;
    int col = lane & 15, quad = lane >> 4;

#pragma unroll
    for (int it = 0; it < 2; it++) {
        int r0 = (it == 0) ? k : (127 - k);  // zig-zag pair: long item first
        int nt = 15 - (r0 >> 3);
        int dt = r0 & 7;
        int n0 = nt * 128, d0 = dt * 128;
        const unsigned short* Ab = attn + (size_t)b * NN * NN + (size_t)n0 * NN;
        const unsigned short* Bb = x0t + (size_t)b * DD * NN + (size_t)d0 * NN;

        floatx4 acc[4][4];
#pragma unroll
        for (int i = 0; i < 4; i++)
#pragma unroll
            for (int jj = 0; jj < 4; jj++) acc[i][jj] = (floatx4)0.0f;

        gemm_reg(Ab, NN, Bb, NN, (nt + 1) * 2, acc);

#pragma unroll
        for (int ti = 0; ti < 4; ti++)
#pragma unroll
            for (int tj = 0; tj < 4; tj++)
#pragma unroll
                for (int rr = 0; rr < 4; rr++) {
                    int n = n0 + wr + ti * 16 + quad * 4 + rr;
                    int d = d0 + wc + tj * 16 + col;
                    float x1 = x[((size_t)b * NN + n) * DD2 + DD + d];
                    out[((size_t)b * NN + n) * DD + d] = acc[ti][tj][rr] * x1;
                }
    }
}

extern "C" void kernel_launch(void* const* d_in, const int* in_sizes, int n_in,
                              void* d_out, int out_size, void* d_ws, size_t ws_size,
                              hipStream_t stream) {
    const float* x  = (const float*)d_in[0];
    const float* sp = (const float*)d_in[1];
    float* out = (float*)d_out;

    unsigned short* xn   = (unsigned short*)d_ws;                      // 33.5 MB
    unsigned short* x0t  = xn + (size_t)NB * NN * DD;                  // 33.5 MB
    unsigned short* attn = x0t + (size_t)NB * NN * DD;                 // 67 MB

    hipLaunchKernelGGL(k_norm,      dim3(NB * NN / 4), dim3(256), 0, stream, x, xn);
    hipLaunchKernelGGL(k_transpose, dim3(512, NB),     dim3(256), 0, stream, x, x0t);
    hipLaunchKernelGGL(k_cosim,     dim3(136 * NB),    dim3(256), 0, stream, xn, sp, attn);
    hipLaunchKernelGGL(k_ctx,       dim3(128 * NB),    dim3(256), 0, stream, attn, x0t, x, out);
}